// Round 9
// baseline (2565.848 us; speedup 1.0000x reference)
//
#include <hip/hip_runtime.h>
#include <hip/hip_bf16.h>
#include <math.h>

// Problem dims (fixed)
#define T_STEPS 512
#define IN_DIM  1024
#define H_DIM   2048
#define Y_DIM   1024

// K2 geometry: 128 blocks x 512 threads (8 waves). Block owns 16 columns,
// wave w owns columns j0 = 16*blockIdx + 2w, j0+1. Weights in VGPRs.
// 82 KB LDS forces 1 block/CU.
#define NBLK2 128
#define BT2   512
#define NWORD (H_DIM / 2)     // 1024 packed transit words per step

// ---------- helpers ----------
static __device__ __forceinline__ unsigned f2bf(float f) {
    unsigned u = __float_as_uint(f);
    return ((u + 0x7FFFu + ((u >> 16) & 1u)) >> 16) & 0xFFFFu;   // RNE
}
static __device__ __forceinline__ float bflo(unsigned p) { return __uint_as_float(p << 16); }
static __device__ __forceinline__ float bfhi(unsigned p) { return __uint_as_float(p & 0xFFFF0000u); }

// s_sleep needs a LITERAL imm -> constant-per-arm backoff ladder
static __device__ __forceinline__ void sleep_bk(int r) {
    switch (r) {
        case 0: break;                                   // immediate recheck
        case 1: __builtin_amdgcn_s_sleep(1); break;      // ~64 cy
        case 2: __builtin_amdgcn_s_sleep(2); break;      // ~128 cy
        case 3: __builtin_amdgcn_s_sleep(4); break;      // ~256 cy
        case 4: __builtin_amdgcn_s_sleep(8); break;      // ~512 cy
        default: __builtin_amdgcn_s_sleep(16); break;    // ~1024 cy
    }
}

// ---------- K1 / K3: tiled fp32 GEMM, C[M,N] = A[M,K] @ B[K,N] + bias[N] ----------
#define TM 64
#define TN 128
#define TK 16

__global__ __launch_bounds__(256) void gemm_bias(
    const float* __restrict__ A, const float* __restrict__ B,
    const float* __restrict__ bias, float* __restrict__ C,
    int M, int N, int K, int lda, int ldb, int ldc)
{
    __shared__ float As[TK][TM + 4];
    __shared__ float Bs[TK][TN + 4];

    const int n0 = blockIdx.x * TN;
    const int m0 = blockIdx.y * TM;
    const int tid = threadIdx.x;
    const int tx = tid & 15;        // N: 8 floats each
    const int ty = tid >> 4;        // M: 4 rows each

    float acc[4][8] = {};

    for (int k0 = 0; k0 < K; k0 += TK) {
        {
            int mm = tid & 63, kq = tid >> 6;
            float4 a = *(const float4*)&A[(m0 + mm) * lda + k0 + 4 * kq];
            As[4 * kq + 0][mm] = a.x;
            As[4 * kq + 1][mm] = a.y;
            As[4 * kq + 2][mm] = a.z;
            As[4 * kq + 3][mm] = a.w;
        }
        #pragma unroll
        for (int l = tid; l < 512; l += 256) {
            int kk = l >> 5, jj = (l & 31) * 4;
            *(float4*)&Bs[kk][jj] = *(const float4*)&B[(k0 + kk) * ldb + n0 + jj];
        }
        __syncthreads();
        #pragma unroll
        for (int kk = 0; kk < TK; ++kk) {
            float4 a  = *(const float4*)&As[kk][ty * 4];
            float4 b0 = *(const float4*)&Bs[kk][tx * 8];
            float4 b1 = *(const float4*)&Bs[kk][tx * 8 + 4];
            const float av[4] = {a.x, a.y, a.z, a.w};
            const float bv[8] = {b0.x, b0.y, b0.z, b0.w, b1.x, b1.y, b1.z, b1.w};
            #pragma unroll
            for (int r = 0; r < 4; ++r)
                #pragma unroll
                for (int c = 0; c < 8; ++c)
                    acc[r][c] = fmaf(av[r], bv[c], acc[r][c]);
        }
        __syncthreads();
    }

    float4 bv0 = *(const float4*)&bias[n0 + tx * 8];
    float4 bv1 = *(const float4*)&bias[n0 + tx * 8 + 4];
    const float bb[8] = {bv0.x, bv0.y, bv0.z, bv0.w, bv1.x, bv1.y, bv1.z, bv1.w};
    #pragma unroll
    for (int r = 0; r < 4; ++r) {
        float4 o0, o1;
        o0.x = acc[r][0] + bb[0]; o0.y = acc[r][1] + bb[1];
        o0.z = acc[r][2] + bb[2]; o0.w = acc[r][3] + bb[3];
        o1.x = acc[r][4] + bb[4]; o1.y = acc[r][5] + bb[5];
        o1.z = acc[r][6] + bb[6]; o1.w = acc[r][7] + bb[7];
        float* cp = &C[(m0 + ty * 4 + r) * ldc + n0 + tx * 8];
        *(float4*)cp = o0;
        *(float4*)(cp + 4) = o1;
    }
}

// ---------- K2: barrier-free dataflow recurrence, single-poller acquire ----------
// (1) ONLY WAVE 0 polls the 1024 transit words (16/lane, batch-issued loads ->
// one RT per retry round), decodes bf16->f32 into LDS; waves 1..7 wait at the
// per-step __syncthreads. Fabric poll load /8 vs R7. (2) Exponential backoff
// (constant-imm ladder) kills the metastable poll-congestion collapse seen in
// R7 (2 of 70 dispatches at 42.9ms). (3) XU/XC prefetched one step ahead.
__global__ __launch_bounds__(BT2) void gru_seq(
    const float* __restrict__ Wu_h,   // = Wu + IN_DIM*H_DIM  (h-part rows)
    const float* __restrict__ Wc_h,
    const float* __restrict__ XU,     // [T,H]  x@Wu_x + bu
    const float* __restrict__ XC,     // [T,H]  x@Wc_x + bc
    const float* __restrict__ h0,     // [H]
    unsigned long long* __restrict__ Hp,  // [T,NWORD] packed transit words
    float* __restrict__ H)                // [T,H] plain f32 (for K3)
{
    // 2 x 10496 floats = 82 KB total: forces exactly 1 block/CU.
    __shared__ float hbuf[2][10496];

    const int tid  = threadIdx.x;
    const int w    = tid >> 6;
    const int lane = tid & 63;
    const int jb   = blockIdx.x * 16;
    const int j0   = jb + 2 * w;

    // ---- one-time weight staging into 64 VGPRs ----
    // Iteration q of compute reads h elements e..e+3, e = 4*(q*64+lane).
    unsigned wru0[16], wru1[16], wrc0[16], wrc1[16];
    #pragma unroll
    for (int q = 0; q < 8; ++q) {
        int e = 4 * (q * 64 + lane);
        const float* u = Wu_h + (size_t)e * H_DIM + j0;
        const float* c = Wc_h + (size_t)e * H_DIM + j0;
        wru0[2*q]   = f2bf(u[0])               | (f2bf(u[(size_t)H_DIM])      << 16);
        wru0[2*q+1] = f2bf(u[2*(size_t)H_DIM]) | (f2bf(u[3*(size_t)H_DIM])    << 16);
        wru1[2*q]   = f2bf(u[1])               | (f2bf(u[(size_t)H_DIM+1])    << 16);
        wru1[2*q+1] = f2bf(u[2*(size_t)H_DIM+1]) | (f2bf(u[3*(size_t)H_DIM+1]) << 16);
        wrc0[2*q]   = f2bf(c[0])               | (f2bf(c[(size_t)H_DIM])      << 16);
        wrc0[2*q+1] = f2bf(c[2*(size_t)H_DIM]) | (f2bf(c[3*(size_t)H_DIM])    << 16);
        wrc1[2*q]   = f2bf(c[1])               | (f2bf(c[(size_t)H_DIM+1])    << 16);
        wrc1[2*q+1] = f2bf(c[2*(size_t)H_DIM+1]) | (f2bf(c[3*(size_t)H_DIM+1]) << 16);
    }

    // carried f32 h for this wave's own columns (lane0's copy authoritative)
    float hc0 = h0[j0], hc1 = h0[j0 + 1];
    const int myword = blockIdx.x * 8 + w;     // published word index

    // XU/XC prefetch registers (step 0 values)
    float2 xu_cur = make_float2(0.f, 0.f), xc_cur = make_float2(0.f, 0.f);
    if (lane == 0) {
        xu_cur = *(const float2*)(XU + j0);
        xc_cur = *(const float2*)(XC + j0);
    }

    for (int t = 0; t < T_STEPS; ++t) {
        // issue prefetch for step t+1 now; consumed next iteration
        float2 xu_nxt = make_float2(0.f, 0.f), xc_nxt = make_float2(0.f, 0.f);
        if (lane == 0 && t + 1 < T_STEPS) {
            xu_nxt = *(const float2*)(XU + (size_t)(t + 1) * H_DIM + j0);
            xc_nxt = *(const float2*)(XC + (size_t)(t + 1) * H_DIM + j0);
        }

        float* hb = hbuf[t & 1];

        // ---- acquire h[t-1] into LDS ----
        if (t == 0) {
            *(float4*)&hb[4 * tid] = *(const float4*)&h0[4 * tid];
        } else if (w == 0) {
            // wave 0 only: poll 16 words/lane, batch-issued, exp backoff
            const unsigned long long* src = Hp + (size_t)(t - 1) * NWORD;
            const unsigned tag = (unsigned)t;
            unsigned long long v[16];
            #pragma unroll
            for (int i = 0; i < 16; ++i)
                v[i] = __hip_atomic_load(src + i * 64 + lane,
                                         __ATOMIC_RELAXED, __HIP_MEMORY_SCOPE_AGENT);
            unsigned mask = 0;
            #pragma unroll
            for (int i = 0; i < 16; ++i)
                mask |= ((unsigned)(v[i] >> 32) != tag) ? (1u << i) : 0u;

            int rnd = 0;
            while (__any(mask != 0u)) {
                sleep_bk(rnd);
                if (rnd < 5) ++rnd;
                #pragma unroll
                for (int i = 0; i < 16; ++i)
                    if (mask & (1u << i))
                        v[i] = __hip_atomic_load(src + i * 64 + lane,
                                                 __ATOMIC_RELAXED, __HIP_MEMORY_SCOPE_AGENT);
                #pragma unroll
                for (int i = 0; i < 16; ++i)
                    if ((mask & (1u << i)) && (unsigned)(v[i] >> 32) == tag)
                        mask &= ~(1u << i);
            }
            // decode bf16 pairs -> f32 LDS (conflict-free: 8B/lane, 512B stride)
            #pragma unroll
            for (int i = 0; i < 16; ++i) {
                unsigned lo = (unsigned)v[i];
                *(float2*)&hb[2 * (i * 64 + lane)] = make_float2(bflo(lo), bfhi(lo));
            }
        }
        __syncthreads();   // h[t-1] fully in LDS; waves 1..7 waited here

        // ---- 4 dot products: 8x ds_read_b128 + 16 FMA per iteration ----
        float au0 = 0.f, au1 = 0.f, ac0 = 0.f, ac1 = 0.f;
        #pragma unroll
        for (int q = 0; q < 8; ++q) {
            float4 h4 = *(const float4*)&hb[4 * (q * 64 + lane)];
            unsigned a, b;
            a = wru0[2*q]; b = wru0[2*q+1];
            au0 = fmaf(h4.x, bflo(a), au0); au0 = fmaf(h4.y, bfhi(a), au0);
            au0 = fmaf(h4.z, bflo(b), au0); au0 = fmaf(h4.w, bfhi(b), au0);
            a = wru1[2*q]; b = wru1[2*q+1];
            au1 = fmaf(h4.x, bflo(a), au1); au1 = fmaf(h4.y, bfhi(a), au1);
            au1 = fmaf(h4.z, bflo(b), au1); au1 = fmaf(h4.w, bfhi(b), au1);
            a = wrc0[2*q]; b = wrc0[2*q+1];
            ac0 = fmaf(h4.x, bflo(a), ac0); ac0 = fmaf(h4.y, bfhi(a), ac0);
            ac0 = fmaf(h4.z, bflo(b), ac0); ac0 = fmaf(h4.w, bfhi(b), ac0);
            a = wrc1[2*q]; b = wrc1[2*q+1];
            ac1 = fmaf(h4.x, bflo(a), ac1); ac1 = fmaf(h4.y, bfhi(a), ac1);
            ac1 = fmaf(h4.z, bflo(b), ac1); ac1 = fmaf(h4.w, bfhi(b), ac1);
        }
        #pragma unroll
        for (int off = 32; off; off >>= 1) {
            au0 += __shfl_down(au0, off);
            au1 += __shfl_down(au1, off);
            ac0 += __shfl_down(ac0, off);
            ac1 += __shfl_down(ac1, off);
        }

        if (lane == 0) {
            float pu0 = au0 + xu_cur.x, pu1 = au1 + xu_cur.y;
            float pc0 = ac0 + xc_cur.x, pc1 = ac1 + xc_cur.y;
            float ug0 = 1.f / (1.f + __expf(-pu0));
            float ug1 = 1.f / (1.f + __expf(-pu1));
            float e0 = __expf(-2.f * fabsf(pc0));
            float e1 = __expf(-2.f * fabsf(pc1));
            float cg0 = copysignf((1.f - e0) / (1.f + e0), pc0);
            float cg1 = copysignf((1.f - e1) / (1.f + e1), pc1);
            float hn0 = ug0 * cg0 + (1.f - ug0) * hc0;
            float hn1 = ug1 * cg1 + (1.f - ug1) * hc1;
            hc0 = hn0; hc1 = hn1;

            // single tagged publish: epoch + both columns in one 8B word
            unsigned lo = f2bf(hn0) | (f2bf(hn1) << 16);
            __hip_atomic_store(Hp + (size_t)t * NWORD + myword,
                               ((unsigned long long)(unsigned)(t + 1) << 32) | lo,
                               __ATOMIC_RELAXED, __HIP_MEMORY_SCOPE_AGENT);
            // plain f32 copy for K3 (visible at kernel boundary)
            *(float2*)(H + (size_t)t * H_DIM + j0) = make_float2(hn0, hn1);
        }
        xu_cur = xu_nxt; xc_cur = xc_nxt;
        // no trailing barrier: double-buffered hbuf + acquire gating keep it safe
    }
}

extern "C" void kernel_launch(void* const* d_in, const int* in_sizes, int n_in,
                              void* d_out, int out_size, void* d_ws, size_t ws_size,
                              hipStream_t stream)
{
    const float* x   = (const float*)d_in[0];   // [1,512,1024]
    const float* h0  = (const float*)d_in[1];   // [2048]
    const float* Wc  = (const float*)d_in[2];   // [3072,2048]
    const float* Wu  = (const float*)d_in[3];   // [3072,2048]
    const float* bc  = (const float*)d_in[4];   // [2048]
    const float* bu  = (const float*)d_in[5];   // [2048]
    const float* Why = (const float*)d_in[6];   // [2048,1024]
    const float* by  = (const float*)d_in[7];   // [1024]
    float* out = (float*)d_out;                 // ys[512*1024] then h_final[2048]

    float* ws = (float*)d_ws;
    float* XU = ws;                                        // 512*2048 f32
    float* XC = ws + (T_STEPS * H_DIM);                    // 512*2048 f32
    float* H  = ws + 2 * (T_STEPS * H_DIM);                // 512*2048 f32 (plain)
    unsigned long long* Hp =
        (unsigned long long*)(ws + 3 * (T_STEPS * H_DIM)); // 512*1024 x 8B transit

    // K1: XU = x @ Wu[0:1024,:] + bu ; XC = x @ Wc[0:1024,:] + bc
    gemm_bias<<<dim3(H_DIM / TN, T_STEPS / TM), 256, 0, stream>>>(
        x, Wu, bu, XU, T_STEPS, H_DIM, IN_DIM, IN_DIM, H_DIM, H_DIM);
    gemm_bias<<<dim3(H_DIM / TN, T_STEPS / TM), 256, 0, stream>>>(
        x, Wc, bc, XC, T_STEPS, H_DIM, IN_DIM, IN_DIM, H_DIM, H_DIM);

    // K2: barrier-free dataflow recurrence (Hp needs no init: 0xAA poison
    // can never equal a valid epoch 1..512)
    gru_seq<<<NBLK2, BT2, 0, stream>>>(
        Wu + IN_DIM * H_DIM, Wc + IN_DIM * H_DIM, XU, XC, h0, Hp, H);

    // K3: ys = H @ Why + by
    gemm_bias<<<dim3(Y_DIM / TN, T_STEPS / TM), 256, 0, stream>>>(
        H, Why, by, out, T_STEPS, Y_DIM, H_DIM, H_DIM, Y_DIM, Y_DIM);

    // h_final = H[511]
    (void)hipMemcpyAsync(out + T_STEPS * Y_DIM, H + (T_STEPS - 1) * H_DIM,
                         H_DIM * sizeof(float), hipMemcpyDeviceToDevice, stream);
}

// Round 11
// 2371.497 us; speedup vs baseline: 1.0820x; 1.0820x over previous
//
#include <hip/hip_runtime.h>
#include <hip/hip_bf16.h>
#include <math.h>

// Problem dims (fixed)
#define T_STEPS 512
#define IN_DIM  1024
#define H_DIM   2048
#define Y_DIM   1024

// K2 geometry: 128 blocks x 512 threads (8 waves). Block owns 16 h-columns
// (wave w owns j0 = 16*blockIdx + 2w, j0+1) and 8 y-columns (computed by
// waves 1..4 in the poll dead-time). Recurrent weights in VGPRs.
#define NBLK2 128
#define BT2   512
#define NWORD (H_DIM / 2)     // 1024 packed transit words per step

// ---------- helpers ----------
static __device__ __forceinline__ unsigned f2bf(float f) {
    unsigned u = __float_as_uint(f);
    return ((u + 0x7FFFu + ((u >> 16) & 1u)) >> 16) & 0xFFFFu;   // RNE
}
static __device__ __forceinline__ float bflo(unsigned p) { return __uint_as_float(p << 16); }
static __device__ __forceinline__ float bfhi(unsigned p) { return __uint_as_float(p & 0xFFFF0000u); }

// s_sleep needs a LITERAL imm -> constant-per-arm backoff ladder
static __device__ __forceinline__ void sleep_bk(int r) {
    switch (r) {
        case 0: break;
        case 1: __builtin_amdgcn_s_sleep(1); break;
        case 2: __builtin_amdgcn_s_sleep(2); break;
        case 3: __builtin_amdgcn_s_sleep(4); break;
        case 4: __builtin_amdgcn_s_sleep(8); break;
        default: __builtin_amdgcn_s_sleep(16); break;
    }
}

// ---------- K1: tiled fp32 GEMM, C[M,N] = A[M,K] @ B[K,N] + bias[N] ----------
// TM=32 so K1 (M=512, N=2048) launches 16x16 = 256 blocks (fills all CUs;
// the old TM=64 tile gave only 128 blocks -> half the chip idle).
#define TM 32
#define TN 128
#define TK 16

__global__ __launch_bounds__(256) void gemm_bias(
    const float* __restrict__ A, const float* __restrict__ B,
    const float* __restrict__ bias, float* __restrict__ C,
    int M, int N, int K, int lda, int ldb, int ldc)
{
    __shared__ float As[TK][TM + 4];    // 36-float rows
    __shared__ float Bs[TK][TN + 4];    // 132-float rows

    const int n0 = blockIdx.x * TN;
    const int m0 = blockIdx.y * TM;
    const int tid = threadIdx.x;
    const int tx = tid & 15;        // N: 8 floats each
    const int ty = tid >> 4;        // M: 2 rows each (0..15)

    float acc[2][8] = {};

    for (int k0 = 0; k0 < K; k0 += TK) {
        // A tile 32x16 -> As[kk][mm]; threads 0..127, one float4 each
        if (tid < 128) {
            int mm = tid & 31, kq = tid >> 5;      // kq 0..3
            float4 a = *(const float4*)&A[(m0 + mm) * lda + k0 + 4 * kq];
            As[4 * kq + 0][mm] = a.x;
            As[4 * kq + 1][mm] = a.y;
            As[4 * kq + 2][mm] = a.z;
            As[4 * kq + 3][mm] = a.w;
        }
        // B tile 16x128; two float4 per thread
        #pragma unroll
        for (int l = tid; l < 512; l += 256) {
            int kk = l >> 5, jj = (l & 31) * 4;
            *(float4*)&Bs[kk][jj] = *(const float4*)&B[(k0 + kk) * ldb + n0 + jj];
        }
        __syncthreads();
        #pragma unroll
        for (int kk = 0; kk < TK; ++kk) {
            float2 a2 = *(const float2*)&As[kk][ty * 2];
            float4 b0 = *(const float4*)&Bs[kk][tx * 8];
            float4 b1 = *(const float4*)&Bs[kk][tx * 8 + 4];
            const float bv[8] = {b0.x, b0.y, b0.z, b0.w, b1.x, b1.y, b1.z, b1.w};
            #pragma unroll
            for (int c = 0; c < 8; ++c) {
                acc[0][c] = fmaf(a2.x, bv[c], acc[0][c]);
                acc[1][c] = fmaf(a2.y, bv[c], acc[1][c]);
            }
        }
        __syncthreads();
    }

    float4 bv0 = *(const float4*)&bias[n0 + tx * 8];
    float4 bv1 = *(const float4*)&bias[n0 + tx * 8 + 4];
    const float bb[8] = {bv0.x, bv0.y, bv0.z, bv0.w, bv1.x, bv1.y, bv1.z, bv1.w};
    #pragma unroll
    for (int r = 0; r < 2; ++r) {
        float4 o0, o1;
        o0.x = acc[r][0] + bb[0]; o0.y = acc[r][1] + bb[1];
        o0.z = acc[r][2] + bb[2]; o0.w = acc[r][3] + bb[3];
        o1.x = acc[r][4] + bb[4]; o1.y = acc[r][5] + bb[5];
        o1.z = acc[r][6] + bb[6]; o1.w = acc[r][7] + bb[7];
        float* cp = &C[(m0 + ty * 2 + r) * ldc + n0 + tx * 8];
        *(float4*)cp = o0;
        *(float4*)(cp + 4) = o1;
    }
}

// ---------- K2: dataflow recurrence + fused y-GEMV in poll dead-time ----------
// Sync core identical to R9 (proven stable): single-poller acquire (wave 0,
// 16 words/lane, batch loads, const-imm exp backoff), tagged bf16 transit,
// no device barrier. NEW: block stages its 8 Why columns in LDS; after each
// publish of h[t], waves 1..4 compute y[t-1] = h[t-1] @ Why + by from hbuf
// (time that was pure idle while wave 0 polls). Epilogue does y[511].
// h_final written directly. K3 and the memcpy dispatch are eliminated.
__global__ __launch_bounds__(BT2) void gru_seq(
    const float* __restrict__ Wu_h,   // = Wu + IN_DIM*H_DIM  (h-part rows)
    const float* __restrict__ Wc_h,
    const float* __restrict__ XU,     // [T,H]  x@Wu_x + bu
    const float* __restrict__ XC,     // [T,H]  x@Wc_x + bc
    const float* __restrict__ h0,     // [H]
    const float* __restrict__ Why,    // [H, Y]
    const float* __restrict__ by,     // [Y]
    unsigned long long* __restrict__ Hp,  // [T,NWORD] packed transit words
    float* __restrict__ Y,                // = out: ys[T,Y]
    float* __restrict__ HF)               // = out + T*Y: h_final[H]
{
    // 82 KB hbuf (padded to force 1 block/CU) + 32 KB Why slice = 114 KB
    __shared__ float hbuf[2][10496];
    __shared__ unsigned wy[8][1024];   // [ycol][word] bf16 pairs

    const int tid  = threadIdx.x;
    const int w    = tid >> 6;
    const int lane = tid & 63;
    const int jb   = blockIdx.x * 16;
    const int j0   = jb + 2 * w;
    const int jy   = blockIdx.x * 8;   // block's y-column base

    // ---- one-time recurrent-weight staging into 64 VGPRs ----
    unsigned wru0[16], wru1[16], wrc0[16], wrc1[16];
    #pragma unroll
    for (int q = 0; q < 8; ++q) {
        int e = 4 * (q * 64 + lane);
        const float* u = Wu_h + (size_t)e * H_DIM + j0;
        const float* c = Wc_h + (size_t)e * H_DIM + j0;
        wru0[2*q]   = f2bf(u[0])               | (f2bf(u[(size_t)H_DIM])      << 16);
        wru0[2*q+1] = f2bf(u[2*(size_t)H_DIM]) | (f2bf(u[3*(size_t)H_DIM])    << 16);
        wru1[2*q]   = f2bf(u[1])               | (f2bf(u[(size_t)H_DIM+1])    << 16);
        wru1[2*q+1] = f2bf(u[2*(size_t)H_DIM+1]) | (f2bf(u[3*(size_t)H_DIM+1]) << 16);
        wrc0[2*q]   = f2bf(c[0])               | (f2bf(c[(size_t)H_DIM])      << 16);
        wrc0[2*q+1] = f2bf(c[2*(size_t)H_DIM]) | (f2bf(c[3*(size_t)H_DIM])    << 16);
        wrc1[2*q]   = f2bf(c[1])               | (f2bf(c[(size_t)H_DIM+1])    << 16);
        wrc1[2*q+1] = f2bf(c[2*(size_t)H_DIM+1]) | (f2bf(c[3*(size_t)H_DIM+1]) << 16);
    }

    // ---- one-time Why slice staging into LDS (bf16 pairs) ----
    for (int idx = tid; idx < 8 * 1024; idx += BT2) {
        int c = idx & 7, p = idx >> 3;
        wy[c][p] = f2bf(Why[(size_t)(2 * p) * Y_DIM + jy + c]) |
                   (f2bf(Why[(size_t)(2 * p + 1) * Y_DIM + jy + c]) << 16);
    }

    // per-wave y assignment: waves 1..4 own 2 cols each; wave 0 stays poll-only
    const int cA = (w - 1) * 2, cB = cA + 1;   // valid for w in 1..4
    float byA = 0.f, byB = 0.f;
    if (lane == 0 && w >= 1 && w <= 4) {
        byA = by[jy + cA];
        byB = by[jy + cB];
    }

    float hc0 = h0[j0], hc1 = h0[j0 + 1];
    const int myword = blockIdx.x * 8 + w;

    float2 xu_cur = make_float2(0.f, 0.f), xc_cur = make_float2(0.f, 0.f);
    if (lane == 0) {
        xu_cur = *(const float2*)(XU + j0);
        xc_cur = *(const float2*)(XC + j0);
    }

    for (int t = 0; t < T_STEPS; ++t) {
        float2 xu_nxt = make_float2(0.f, 0.f), xc_nxt = make_float2(0.f, 0.f);
        if (lane == 0 && t + 1 < T_STEPS) {
            xu_nxt = *(const float2*)(XU + (size_t)(t + 1) * H_DIM + j0);
            xc_nxt = *(const float2*)(XC + (size_t)(t + 1) * H_DIM + j0);
        }

        float* hb = hbuf[t & 1];

        // ---- acquire h[t-1] into LDS (wave 0 only) ----
        if (t == 0) {
            *(float4*)&hb[4 * tid] = *(const float4*)&h0[4 * tid];
        } else if (w == 0) {
            const unsigned long long* src = Hp + (size_t)(t - 1) * NWORD;
            const unsigned tag = (unsigned)t;
            unsigned long long v[16];
            #pragma unroll
            for (int i = 0; i < 16; ++i)
                v[i] = __hip_atomic_load(src + i * 64 + lane,
                                         __ATOMIC_RELAXED, __HIP_MEMORY_SCOPE_AGENT);
            unsigned mask = 0;
            #pragma unroll
            for (int i = 0; i < 16; ++i)
                mask |= ((unsigned)(v[i] >> 32) != tag) ? (1u << i) : 0u;

            int rnd = 0;
            while (__any(mask != 0u)) {
                sleep_bk(rnd);
                if (rnd < 5) ++rnd;
                #pragma unroll
                for (int i = 0; i < 16; ++i)
                    if (mask & (1u << i))
                        v[i] = __hip_atomic_load(src + i * 64 + lane,
                                                 __ATOMIC_RELAXED, __HIP_MEMORY_SCOPE_AGENT);
                #pragma unroll
                for (int i = 0; i < 16; ++i)
                    if ((mask & (1u << i)) && (unsigned)(v[i] >> 32) == tag)
                        mask &= ~(1u << i);
            }
            #pragma unroll
            for (int i = 0; i < 16; ++i) {
                unsigned lo = (unsigned)v[i];
                *(float2*)&hb[2 * (i * 64 + lane)] = make_float2(bflo(lo), bfhi(lo));
            }
        }
        __syncthreads();   // h[t-1] in LDS

        // ---- recurrence dots: 8x ds_read_b128 + 16 FMA per iteration ----
        float au0 = 0.f, au1 = 0.f, ac0 = 0.f, ac1 = 0.f;
        #pragma unroll
        for (int q = 0; q < 8; ++q) {
            float4 h4 = *(const float4*)&hb[4 * (q * 64 + lane)];
            unsigned a, b;
            a = wru0[2*q]; b = wru0[2*q+1];
            au0 = fmaf(h4.x, bflo(a), au0); au0 = fmaf(h4.y, bfhi(a), au0);
            au0 = fmaf(h4.z, bflo(b), au0); au0 = fmaf(h4.w, bfhi(b), au0);
            a = wru1[2*q]; b = wru1[2*q+1];
            au1 = fmaf(h4.x, bflo(a), au1); au1 = fmaf(h4.y, bfhi(a), au1);
            au1 = fmaf(h4.z, bflo(b), au1); au1 = fmaf(h4.w, bfhi(b), au1);
            a = wrc0[2*q]; b = wrc0[2*q+1];
            ac0 = fmaf(h4.x, bflo(a), ac0); ac0 = fmaf(h4.y, bfhi(a), ac0);
            ac0 = fmaf(h4.z, bflo(b), ac0); ac0 = fmaf(h4.w, bfhi(b), ac0);
            a = wrc1[2*q]; b = wrc1[2*q+1];
            ac1 = fmaf(h4.x, bflo(a), ac1); ac1 = fmaf(h4.y, bfhi(a), ac1);
            ac1 = fmaf(h4.z, bflo(b), ac1); ac1 = fmaf(h4.w, bfhi(b), ac1);
        }
        #pragma unroll
        for (int off = 32; off; off >>= 1) {
            au0 += __shfl_down(au0, off);
            au1 += __shfl_down(au1, off);
            ac0 += __shfl_down(ac0, off);
            ac1 += __shfl_down(ac1, off);
        }

        if (lane == 0) {
            float pu0 = au0 + xu_cur.x, pu1 = au1 + xu_cur.y;
            float pc0 = ac0 + xc_cur.x, pc1 = ac1 + xc_cur.y;
            float ug0 = 1.f / (1.f + __expf(-pu0));
            float ug1 = 1.f / (1.f + __expf(-pu1));
            float e0 = __expf(-2.f * fabsf(pc0));
            float e1 = __expf(-2.f * fabsf(pc1));
            float cg0 = copysignf((1.f - e0) / (1.f + e0), pc0);
            float cg1 = copysignf((1.f - e1) / (1.f + e1), pc1);
            float hn0 = ug0 * cg0 + (1.f - ug0) * hc0;
            float hn1 = ug1 * cg1 + (1.f - ug1) * hc1;
            hc0 = hn0; hc1 = hn1;

            unsigned lo = f2bf(hn0) | (f2bf(hn1) << 16);
            __hip_atomic_store(Hp + (size_t)t * NWORD + myword,
                               ((unsigned long long)(unsigned)(t + 1) << 32) | lo,
                               __ATOMIC_RELAXED, __HIP_MEMORY_SCOPE_AGENT);
            if (t == T_STEPS - 1) {            // h_final direct
                HF[j0]     = hn0;
                HF[j0 + 1] = hn1;
            }
        }

        // ---- fused y-GEMV in dead time: y[t-1] = h[t-1] @ Why + by ----
        // waves 1..4 (2 cols each); wave 0 goes straight to next poll.
        if (t >= 1 && w >= 1 && w <= 4) {
            float yA = 0.f, yB = 0.f;
            #pragma unroll
            for (int q = 0; q < 8; ++q) {
                float4 h4 = *(const float4*)&hb[4 * (q * 64 + lane)];
                int p = 2 * (q * 64 + lane);
                uint2 wa = *(const uint2*)&wy[cA][p];
                uint2 wb = *(const uint2*)&wy[cB][p];
                yA = fmaf(h4.x, bflo(wa.x), yA); yA = fmaf(h4.y, bfhi(wa.x), yA);
                yA = fmaf(h4.z, bflo(wa.y), yA); yA = fmaf(h4.w, bfhi(wa.y), yA);
                yB = fmaf(h4.x, bflo(wb.x), yB); yB = fmaf(h4.y, bfhi(wb.x), yB);
                yB = fmaf(h4.z, bflo(wb.y), yB); yB = fmaf(h4.w, bfhi(wb.y), yB);
            }
            #pragma unroll
            for (int off = 32; off; off >>= 1) {
                yA += __shfl_down(yA, off);
                yB += __shfl_down(yB, off);
            }
            if (lane == 0) {
                Y[(size_t)(t - 1) * Y_DIM + jy + cA] = yA + byA;
                Y[(size_t)(t - 1) * Y_DIM + jy + cB] = yB + byB;
            }
        }
        xu_cur = xu_nxt; xc_cur = xc_nxt;
    }

    // ---- epilogue: acquire h[511] and compute y[511] ----
    {
        float* hb = hbuf[T_STEPS & 1];   // buffer 0
        if (w == 0) {
            const unsigned long long* src = Hp + (size_t)(T_STEPS - 1) * NWORD;
            const unsigned tag = (unsigned)T_STEPS;
            unsigned long long v[16];
            #pragma unroll
            for (int i = 0; i < 16; ++i)
                v[i] = __hip_atomic_load(src + i * 64 + lane,
                                         __ATOMIC_RELAXED, __HIP_MEMORY_SCOPE_AGENT);
            unsigned mask = 0;
            #pragma unroll
            for (int i = 0; i < 16; ++i)
                mask |= ((unsigned)(v[i] >> 32) != tag) ? (1u << i) : 0u;
            int rnd = 0;
            while (__any(mask != 0u)) {
                sleep_bk(rnd);
                if (rnd < 5) ++rnd;
                #pragma unroll
                for (int i = 0; i < 16; ++i)
                    if (mask & (1u << i))
                        v[i] = __hip_atomic_load(src + i * 64 + lane,
                                                 __ATOMIC_RELAXED, __HIP_MEMORY_SCOPE_AGENT);
                #pragma unroll
                for (int i = 0; i < 16; ++i)
                    if ((mask & (1u << i)) && (unsigned)(v[i] >> 32) == tag)
                        mask &= ~(1u << i);
            }
            #pragma unroll
            for (int i = 0; i < 16; ++i) {
                unsigned lo = (unsigned)v[i];
                *(float2*)&hb[2 * (i * 64 + lane)] = make_float2(bflo(lo), bfhi(lo));
            }
        }
        __syncthreads();

        if (w >= 1 && w <= 4) {
            float yA = 0.f, yB = 0.f;
            #pragma unroll
            for (int q = 0; q < 8; ++q) {
                float4 h4 = *(const float4*)&hb[4 * (q * 64 + lane)];
                int p = 2 * (q * 64 + lane);
                uint2 wa = *(const uint2*)&wy[cA][p];
                uint2 wb = *(const uint2*)&wy[cB][p];
                yA = fmaf(h4.x, bflo(wa.x), yA); yA = fmaf(h4.y, bfhi(wa.x), yA);
                yA = fmaf(h4.z, bflo(wa.y), yA); yA = fmaf(h4.w, bfhi(wa.y), yA);
                yB = fmaf(h4.x, bflo(wb.x), yB); yB = fmaf(h4.y, bfhi(wb.x), yB);
                yB = fmaf(h4.z, bflo(wb.y), yB); yB = fmaf(h4.w, bfhi(wb.y), yB);
            }
            #pragma unroll
            for (int off = 32; off; off >>= 1) {
                yA += __shfl_down(yA, off);
                yB += __shfl_down(yB, off);
            }
            if (lane == 0) {
                Y[(size_t)(T_STEPS - 1) * Y_DIM + jy + cA] = yA + byA;
                Y[(size_t)(T_STEPS - 1) * Y_DIM + jy + cB] = yB + byB;
            }
        }
    }
}

extern "C" void kernel_launch(void* const* d_in, const int* in_sizes, int n_in,
                              void* d_out, int out_size, void* d_ws, size_t ws_size,
                              hipStream_t stream)
{
    const float* x   = (const float*)d_in[0];   // [1,512,1024]
    const float* h0  = (const float*)d_in[1];   // [2048]
    const float* Wc  = (const float*)d_in[2];   // [3072,2048]
    const float* Wu  = (const float*)d_in[3];   // [3072,2048]
    const float* bc  = (const float*)d_in[4];   // [2048]
    const float* bu  = (const float*)d_in[5];   // [2048]
    const float* Why = (const float*)d_in[6];   // [2048,1024]
    const float* by  = (const float*)d_in[7];   // [1024]
    float* out = (float*)d_out;                 // ys[512*1024] then h_final[2048]

    float* ws = (float*)d_ws;
    float* XU = ws;                                        // 512*2048 f32
    float* XC = ws + (T_STEPS * H_DIM);                    // 512*2048 f32
    unsigned long long* Hp =
        (unsigned long long*)(ws + 2 * (T_STEPS * H_DIM)); // 512*1024 x 8B transit

    // K1: XU = x @ Wu[0:1024,:] + bu ; XC = x @ Wc[0:1024,:] + bc  (256 blocks each)
    gemm_bias<<<dim3(H_DIM / TN, T_STEPS / TM), 256, 0, stream>>>(
        x, Wu, bu, XU, T_STEPS, H_DIM, IN_DIM, IN_DIM, H_DIM, H_DIM);
    gemm_bias<<<dim3(H_DIM / TN, T_STEPS / TM), 256, 0, stream>>>(
        x, Wc, bc, XC, T_STEPS, H_DIM, IN_DIM, IN_DIM, H_DIM, H_DIM);

    // K2: dataflow recurrence + fused y-GEMV (Hp needs no init: 0xAA poison
    // can never equal a valid epoch 1..512). K3 and memcpy eliminated.
    gru_seq<<<NBLK2, BT2, 0, stream>>>(
        Wu + IN_DIM * H_DIM, Wc + IN_DIM * H_DIM, XU, XC, h0, Why, by,
        Hp, out, out + (size_t)T_STEPS * Y_DIM);
}